// Round 3
// baseline (229.913 us; speedup 1.0000x reference)
//
#include <hip/hip_runtime.h>

// 16 lanes per batch element; 1 hidden unit per lane (10 real + 6 dummy).
#define LPE 16
#define CH 16   // steps per software-pipeline chunk

#if __has_builtin(__builtin_amdgcn_exp2f)
  #define EXP2F(x) __builtin_amdgcn_exp2f(x)
#else
  #define EXP2F(x) exp2f(x)
#endif
#if __has_builtin(__builtin_amdgcn_rcpf)
  #define RCPF(x) __builtin_amdgcn_rcpf(x)
#else
  #define RCPF(x) (1.0f/(x))
#endif

template<int CTRL>
__device__ __forceinline__ float dpp_add(float x) {
    int y = __builtin_amdgcn_update_dpp(0, __float_as_int(x), CTRL, 0xF, 0xF, true);
    return x + __int_as_float(y);
}
// Butterfly sum across each aligned 16-lane group; all 16 lanes get the total.
__device__ __forceinline__ float reduce16(float x) {
    x = dpp_add<0xB1>(x);   // quad_perm(1,0,3,2): xor 1
    x = dpp_add<0x4E>(x);   // quad_perm(2,3,0,1): xor 2
    x = dpp_add<0x141>(x);  // row_half_mirror   : completes aligned-8 sums
    x = dpp_add<0x140>(x);  // row_mirror        : completes aligned-16 sums
    return x;
}

__global__ __launch_bounds__(256, 1) void ode_scan(
    const float* __restrict__ t,
    const float* __restrict__ Vs,
    const float* __restrict__ Tm,
    const float* __restrict__ C0,
    const float* __restrict__ R0,
    const float* __restrict__ W1,   // (5,10)
    const float* __restrict__ b1,   // (10)
    const float* __restrict__ W2,   // (10,5)
    const float* __restrict__ b2,   // (5)
    float* __restrict__ out,        // (B, N+1, 2)
    int B, int N)
{
    int tid = blockIdx.x * blockDim.x + threadIdx.x;
    int e = tid >> 4;      // element
    int u = tid & 15;      // unit index j == u
    if (e >= B) return;

    const float S = 2.88539008177792681472f;   // 2*log2(e)
    float Vv = Vs[e], Tv = Tm[e];

    // Per-lane folded weights for hidden unit j = u.
    float w0s, w3s, w4s, cc, v3, v4;
    if (u < 10) {
        w0s = S*W1[u]; w3s = S*W1[30+u]; w4s = S*W1[40+u];
        cc  = S*fmaf(Vv, W1[10+u], fmaf(Tv, W1[20+u], b1[u]));
        v3  = -2.0f*W2[5*u+3]; v4 = -2.0f*W2[5*u+4];
    } else if (u == 10) {
        // constant unit: a = -60 -> z = 2^-60 -> 1+z == 1.0f -> r == 1.0 exactly
        w0s = 0.f; w3s = 0.f; w4s = 0.f; cc = -60.f;
        float c3 = b2[3], c4 = b2[4];
        for (int j = 0; j < 10; ++j) { c3 += W2[5*j+3]; c4 += W2[5*j+4]; }
        v3 = c3; v4 = c4;
    } else {
        w0s = 0.f; w3s = 0.f; w4s = 0.f; cc = -60.f; v3 = 0.f; v4 = 0.f;
    }

    float Cap = C0[e], Res = R0[e];
    const float* trow = t + (size_t)e * (N + 1);
    float* orow = out + (size_t)e * (size_t)(N + 1) * 2;
    *(float2*)orow = make_float2(Cap, Res);

    // Serial chain: Cap/Res -> 2 fma -> exp2 -> add -> rcp -> mul -> reduce16 -> fma.
#define STEP(HH, TP, DST) do {                                              \
        float a_ = fmaf(Res, w4s, fmaf(Cap, w3s, (TP)));                    \
        float r_ = RCPF(EXP2F(a_) + 1.0f);                                  \
        float p3_ = reduce16(r_ * v3);                                      \
        float p4_ = reduce16(r_ * v4);                                      \
        Cap = fmaf((HH), p3_, Cap);                                         \
        Res = fmaf((HH), p4_, Res);                                         \
        (DST) = make_float2(Cap, Res);                                      \
    } while (0)

#define LOADCH(RAW, BASE) do {                                              \
        _Pragma("unroll")                                                   \
        for (int m_ = 0; m_ < CH; ++m_) {                                   \
            int idx_ = (BASE) + m_; idx_ = idx_ > N ? N : idx_;             \
            (RAW)[m_] = trow[idx_];                                         \
        }                                                                   \
    } while (0)

    // h[m] = t_i - t_{i-1};  tp[m] = fma(t_{i-1}, w0s, cc)
#define DERIVE(H, TP, RAW, CARRY) do {                                      \
        float prev_ = (CARRY);                                              \
        _Pragma("unroll")                                                   \
        for (int m_ = 0; m_ < CH; ++m_) {                                   \
            (H)[m_]  = (RAW)[m_] - prev_;                                   \
            (TP)[m_] = fmaf(prev_, w0s, cc);                                \
            prev_ = (RAW)[m_];                                              \
        }                                                                   \
    } while (0)

#define PROC(H, TP, OP) do {                                                \
        _Pragma("unroll")                                                   \
        for (int m_ = 0; m_ < CH; ++m_) STEP((H)[m_], (TP)[m_], (OP)[m_]);  \
    } while (0)

    int i = 1;
    if (N >= 2*CH) {
        float rawA[CH], rawB[CH];
        float hA[CH], tA[CH];
        float hB[CH], tB[CH];

        float tfirst = trow[0];
        LOADCH(rawA, 1);            // chunk 0
        LOADCH(rawB, 1 + CH);       // chunk 1
        DERIVE(hA, tA, rawA, tfirst);
        float carryB = rawA[CH-1];
        DERIVE(hB, tB, rawB, carryB);
        LOADCH(rawA, 1 + 2*CH);     // chunk 2 in flight

        int npair = N / (2*CH);
        float2* op = (float2*)orow + 1;
        for (int p = 0; p < npair; ++p) {
            int c = 2*p;
            PROC(hA, tA, op);
            op += CH;
            DERIVE(hA, tA, rawA, rawB[CH-1]);    // derive chunk c+2
            LOADCH(rawB, 1 + (c + 3)*CH);        // chunk c+3 in flight
            PROC(hB, tB, op);
            op += CH;
            DERIVE(hB, tB, rawB, rawA[CH-1]);    // derive chunk c+3
            LOADCH(rawA, 1 + (c + 4)*CH);        // chunk c+4 in flight
        }
        i = 2*CH*npair + 1;
    }
    // generic scalar tail (not hit for N=2048)
    for (; i <= N; ++i) {
        float tcv = trow[i-1];
        float h_  = trow[i] - tcv;
        float tp_ = fmaf(tcv, w0s, cc);
        STEP(h_, tp_, *(float2*)(orow + 2*(size_t)i));
    }
#undef STEP
#undef LOADCH
#undef DERIVE
#undef PROC
}

extern "C" void kernel_launch(void* const* d_in, const int* in_sizes, int n_in,
                              void* d_out, int out_size, void* d_ws, size_t ws_size,
                              hipStream_t stream) {
    const float* t  = (const float*)d_in[0];
    const float* Vs = (const float*)d_in[1];
    const float* Tm = (const float*)d_in[2];
    const float* C0 = (const float*)d_in[3];
    const float* R0 = (const float*)d_in[4];
    const float* W1 = (const float*)d_in[5];
    const float* b1 = (const float*)d_in[6];
    const float* W2 = (const float*)d_in[7];
    const float* b2 = (const float*)d_in[8];
    float* out = (float*)d_out;

    int B = in_sizes[1];
    int N = in_sizes[0] / B - 1;

    int threads = B * LPE;
    dim3 block(256);
    dim3 grid((threads + 255) / 256);
    hipLaunchKernelGGL(ode_scan, grid, block, 0, stream,
                       t, Vs, Tm, C0, R0, W1, b1, W2, b2, out, B, N);
}

// Round 4
// 150.615 us; speedup vs baseline: 1.5265x; 1.5265x over previous
//
#include <hip/hip_runtime.h>

// 8 lanes per batch element; 2 hidden units per lane packed as float2 (VOP3P).
#define LPE 8
#define CH 16   // steps per prefetch chunk

typedef float v2f __attribute__((ext_vector_type(2)));

#if __has_builtin(__builtin_amdgcn_exp2f)
  #define EXP2F(x) __builtin_amdgcn_exp2f(x)
#else
  #define EXP2F(x) exp2f(x)
#endif
#if __has_builtin(__builtin_amdgcn_rcpf)
  #define RCPF(x) __builtin_amdgcn_rcpf(x)
#else
  #define RCPF(x) (1.0f/(x))
#endif

template<int CTRL>
__device__ __forceinline__ float dpp_add(float x) {
    int y = __builtin_amdgcn_update_dpp(0, __float_as_int(x), CTRL, 0xF, 0xF, true);
    return x + __int_as_float(y);
}

__device__ __forceinline__ v2f vfma(v2f a, v2f b, v2f c) {
#if __has_builtin(__builtin_elementwise_fma)
    return __builtin_elementwise_fma(a, b, c);
#else
    v2f r; r.x = fmaf(a.x, b.x, c.x); r.y = fmaf(a.y, b.y, c.y); return r;
#endif
}

__global__ __launch_bounds__(256, 1) void ode_scan(
    const float* __restrict__ t,
    const float* __restrict__ Vs,
    const float* __restrict__ Tm,
    const float* __restrict__ C0,
    const float* __restrict__ R0,
    const float* __restrict__ W1,   // (5,10)
    const float* __restrict__ b1,   // (10)
    const float* __restrict__ W2,   // (10,5)
    const float* __restrict__ b2,   // (5)
    float* __restrict__ out,        // (B, N+1, 2)
    int B, int N)
{
    int tid = blockIdx.x * blockDim.x + threadIdx.x;
    int e = tid >> 3;
    int u = tid & 7;
    if (e >= B) return;

    const float S = 2.88539008177792681472f;   // 2*log2(e)
    float Vv = Vs[e], Tv = Tm[e];

    // Packed per-lane weights for hidden units j0=2u (x), j1=2u+1 (y).
    v2f W0p, W3p, W4p, CCp, V3p, V4p;
    {
        int j0 = 2*u, j1 = 2*u + 1;
        if (j0 < 10) {
            W0p.x = S*W1[j0]; W3p.x = S*W1[30+j0]; W4p.x = S*W1[40+j0];
            CCp.x = S*fmaf(Vv, W1[10+j0], fmaf(Tv, W1[20+j0], b1[j0]));
            V3p.x = -2.0f*W2[5*j0+3]; V4p.x = -2.0f*W2[5*j0+4];
        } else { W0p.x=0.f; W3p.x=0.f; W4p.x=0.f; CCp.x=-60.f; V3p.x=0.f; V4p.x=0.f; }
        if (j1 < 10) {
            W0p.y = S*W1[j1]; W3p.y = S*W1[30+j1]; W4p.y = S*W1[40+j1];
            CCp.y = S*fmaf(Vv, W1[10+j1], fmaf(Tv, W1[20+j1], b1[j1]));
            V3p.y = -2.0f*W2[5*j1+3]; V4p.y = -2.0f*W2[5*j1+4];
        } else { W0p.y=0.f; W3p.y=0.f; W4p.y=0.f; CCp.y=-60.f; V3p.y=0.f; V4p.y=0.f; }
        if (j0 == 10) {
            // dummy constant unit: a=-60 -> z=2^-60 -> 1+z==1.0f -> r==1.0 exactly
            float c3 = b2[3], c4 = b2[4];
            for (int j = 0; j < 10; ++j) { c3 += W2[5*j+3]; c4 += W2[5*j+4]; }
            V3p.x = c3; V4p.x = c4;
        }
    }

    float Cap = C0[e], Res = R0[e];
    const float* trow = t + (size_t)e * (N + 1);
    float* orow = out + (size_t)e * (size_t)(N + 1) * 2;
    *(float2*)orow = make_float2(Cap, Res);
    float tprev = trow[0];

    // One scan step; h/tp are t-only (off the Cap/Res chain), computed in-step.
    auto step = [&](float tn, float2& dst) {
        float h = tn - tprev;
        v2f tpv; tpv.x = tprev; tpv.y = tprev;
        v2f capv; capv.x = Cap; capv.y = Cap;
        v2f resv; resv.x = Res; resv.y = Res;
        v2f TP = vfma(tpv, W0p, CCp);
        v2f A  = vfma(resv, W4p, vfma(capv, W3p, TP));
        float z0 = EXP2F(A.x);
        float z1 = EXP2F(A.y);
        float r0 = RCPF(z0 + 1.0f);
        float r1 = RCPF(z1 + 1.0f);
        float p3 = fmaf(r1, V3p.y, r0 * V3p.x);
        float p4 = fmaf(r1, V4p.y, r0 * V4p.x);
        // interleaved 3-stage butterflies (aligned 8-lane groups)
        p3 = dpp_add<0xB1>(p3);  p4 = dpp_add<0xB1>(p4);   // xor 1
        p3 = dpp_add<0x4E>(p3);  p4 = dpp_add<0x4E>(p4);   // xor 2
        p3 = dpp_add<0x141>(p3); p4 = dpp_add<0x141>(p4);  // row_half_mirror
        Cap = fmaf(h, p3, Cap);
        Res = fmaf(h, p4, Res);
        tprev = tn;
        dst = make_float2(Cap, Res);
    };

    int i = 1;
    if (N >= 2*CH) {
        float rawA[CH], rawB[CH];
        int nch = N / CH;           // full chunks; pair-process (nch even for N=2048)
        int npair = nch / 2;
        int lim = N + 1 - CH;       // max valid load base

#pragma unroll
        for (int m = 0; m < CH; ++m) rawA[m] = trow[1 + m];   // chunk 0

        float2* op = (float2*)orow + 1;
        for (int p = 0; p < npair; ++p) {
            int c = 2*p;
            {   // process chunk c (rawA), prefetch chunk c+1 into rawB
                int base = (c + 1)*CH + 1; if (base > lim) base = lim;
                const float* lp = trow + base;
#pragma unroll
                for (int m = 0; m < CH; ++m) { rawB[m] = lp[m]; step(rawA[m], op[m]); }
                op += CH;
            }
            {   // process chunk c+1 (rawB), prefetch chunk c+2 into rawA
                int base = (c + 2)*CH + 1; if (base > lim) base = lim;
                const float* lp = trow + base;
#pragma unroll
                for (int m = 0; m < CH; ++m) { rawA[m] = lp[m]; step(rawB[m], op[m]); }
                op += CH;
            }
        }
        i = 2*CH*npair + 1;
    }
    // scalar tail (not hit for N=2048)
    for (; i <= N; ++i) {
        step(trow[i], *(float2*)(orow + 2*(size_t)i));
    }
}

extern "C" void kernel_launch(void* const* d_in, const int* in_sizes, int n_in,
                              void* d_out, int out_size, void* d_ws, size_t ws_size,
                              hipStream_t stream) {
    const float* t  = (const float*)d_in[0];
    const float* Vs = (const float*)d_in[1];
    const float* Tm = (const float*)d_in[2];
    const float* C0 = (const float*)d_in[3];
    const float* R0 = (const float*)d_in[4];
    const float* W1 = (const float*)d_in[5];
    const float* b1 = (const float*)d_in[6];
    const float* W2 = (const float*)d_in[7];
    const float* b2 = (const float*)d_in[8];
    float* out = (float*)d_out;

    int B = in_sizes[1];
    int N = in_sizes[0] / B - 1;

    int threads = B * LPE;
    dim3 block(256);
    dim3 grid((threads + 255) / 256);
    hipLaunchKernelGGL(ode_scan, grid, block, 0, stream,
                       t, Vs, Tm, C0, R0, W1, b1, W2, b2, out, B, N);
}

// Round 5
// 145.148 us; speedup vs baseline: 1.5840x; 1.0377x over previous
//
#include <hip/hip_runtime.h>

// 8 lanes per batch element; 2 hidden units per lane packed as float2 (VOP3P).
// Steady-state steps use incremental z/r recurrences (no transcendentals);
// exact exp2+rcp resync every RS steps bounds rounding drift.
#define LPE 8
#define CH 16   // steps per prefetch chunk
#define RS 4    // resync period (must divide CH)

typedef float v2f __attribute__((ext_vector_type(2)));

#if __has_builtin(__builtin_amdgcn_exp2f)
  #define EXP2F(x) __builtin_amdgcn_exp2f(x)
#else
  #define EXP2F(x) exp2f(x)
#endif
#if __has_builtin(__builtin_amdgcn_rcpf)
  #define RCPF(x) __builtin_amdgcn_rcpf(x)
#else
  #define RCPF(x) (1.0f/(x))
#endif

template<int CTRL>
__device__ __forceinline__ float dpp_add(float x) {
    int y = __builtin_amdgcn_update_dpp(0, __float_as_int(x), CTRL, 0xF, 0xF, true);
    return x + __int_as_float(y);
}

__device__ __forceinline__ v2f vfma(v2f a, v2f b, v2f c) {
#if __has_builtin(__builtin_elementwise_fma)
    return __builtin_elementwise_fma(a, b, c);
#else
    v2f r; r.x = fmaf(a.x, b.x, c.x); r.y = fmaf(a.y, b.y, c.y); return r;
#endif
}
__device__ __forceinline__ v2f splat(float x) { v2f v; v.x = x; v.y = x; return v; }

__global__ __launch_bounds__(256, 1) void ode_scan(
    const float* __restrict__ t,
    const float* __restrict__ Vs,
    const float* __restrict__ Tm,
    const float* __restrict__ C0,
    const float* __restrict__ R0,
    const float* __restrict__ W1,   // (5,10)
    const float* __restrict__ b1,   // (10)
    const float* __restrict__ W2,   // (10,5)
    const float* __restrict__ b2,   // (5)
    float* __restrict__ out,        // (B, N+1, 2)
    int B, int N)
{
    int tid = blockIdx.x * blockDim.x + threadIdx.x;
    int e = tid >> 3;
    int u = tid & 7;
    if (e >= B) return;

    const float S = 2.88539008177792681472f;   // 2*log2(e)
    float Vv = Vs[e], Tv = Tm[e];

    // Packed per-lane weights for hidden units j0=2u (x), j1=2u+1 (y).
    v2f W0p, W3p, W4p, CCp, V3p, V4p;
    {
        int j0 = 2*u, j1 = 2*u + 1;
        if (j0 < 10) {
            W0p.x = S*W1[j0]; W3p.x = S*W1[30+j0]; W4p.x = S*W1[40+j0];
            CCp.x = S*fmaf(Vv, W1[10+j0], fmaf(Tv, W1[20+j0], b1[j0]));
            V3p.x = -2.0f*W2[5*j0+3]; V4p.x = -2.0f*W2[5*j0+4];
        } else { W0p.x=0.f; W3p.x=0.f; W4p.x=0.f; CCp.x=-60.f; V3p.x=0.f; V4p.x=0.f; }
        if (j1 < 10) {
            W0p.y = S*W1[j1]; W3p.y = S*W1[30+j1]; W4p.y = S*W1[40+j1];
            CCp.y = S*fmaf(Vv, W1[10+j1], fmaf(Tv, W1[20+j1], b1[j1]));
            V3p.y = -2.0f*W2[5*j1+3]; V4p.y = -2.0f*W2[5*j1+4];
        } else { W0p.y=0.f; W3p.y=0.f; W4p.y=0.f; CCp.y=-60.f; V3p.y=0.f; V4p.y=0.f; }
        if (j0 == 10) {
            // constant unit: a=-60 -> z=2^-60 -> 1+z==1.0f -> r==1.0 exactly;
            // stays exact through the recurrence (delta==0 -> m==1, e==1).
            float c3 = b2[3], c4 = b2[4];
            for (int j = 0; j < 10; ++j) { c3 += W2[5*j+3]; c4 += W2[5*j+4]; }
            V3p.x = c3; V4p.x = c4;
        }
    }

    const v2f ONEv = splat(1.0f);
    const v2f TWOv = splat(2.0f);
    const v2f C1v  = splat(0.69314718055994530942f);   // ln2
    const v2f C2v  = splat(0.24022650695910071233f);   // ln2^2/2
    const v2f C3v  = splat(0.05550410866482157618f);   // ln2^3/6

    float Cap = C0[e], Res = R0[e];
    const float* trow = t + (size_t)e * (N + 1);
    float* orow = out + (size_t)e * (size_t)(N + 1) * 2;
    *(float2*)orow = make_float2(Cap, Res);
    float tprev = trow[0];

    v2f z = splat(0.0f), r = ONEv;   // valid after first (slow) step

    // products + 8-lane reduce + state update + store (shared tail)
    auto tail = [&](float h, float tn, float2& dst, float& p3o, float& p4o) {
        v2f q3 = r * V3p;
        v2f q4 = r * V4p;
        float p3 = q3.x + q3.y;
        float p4 = q4.x + q4.y;
        p3 = dpp_add<0xB1>(p3);  p4 = dpp_add<0xB1>(p4);
        p3 = dpp_add<0x4E>(p3);  p4 = dpp_add<0x4E>(p4);
        p3 = dpp_add<0x141>(p3); p4 = dpp_add<0x141>(p4);
        Cap = fmaf(h, p3, Cap);
        Res = fmaf(h, p4, Res);
        tprev = tn;
        dst = make_float2(Cap, Res);
        p3o = p3; p4o = p4;
    };

    // exact step: recompute z, r from scratch (ground truth, kills drift)
    auto slow_step = [&](float tn, float2& dst) {
        v2f TP = vfma(splat(tprev), W0p, CCp);
        v2f A  = vfma(splat(Res), W4p, vfma(splat(Cap), W3p, TP));
        v2f zz; zz.x = EXP2F(A.x); zz.y = EXP2F(A.y);
        v2f d = zz + ONEv;
        v2f rr; rr.x = RCPF(d.x); rr.y = RCPF(d.y);
        z = zz; r = rr;
        float h = tn - tprev;
        float p3, p4;
        tail(h, tn, dst, p3, p4);
    };

    // incremental step: advance z multiplicatively, r by 2 Newton iterations
    auto fast_step = [&](float tn, float2& dst) {
        float h = tn - tprev;
        float p3, p4;
        tail(h, tn, dst, p3, p4);
        // delta = a_{i+1} - a_i = h*(W3*p3 + W4*p4 + W0)
        v2f G  = vfma(splat(p3), W3p, vfma(splat(p4), W4p, W0p));
        v2f dl = splat(h) * G;
        // z *= 2^delta  ~ 1 + c1 d + c2 d^2 + c3 d^3
        v2f q = vfma(dl, C3v, C2v);
        q = vfma(dl, q, C1v);
        v2f m = vfma(dl, q, ONEv);
        z = z * m;
        // r = 1/(1+z) via 2 Newton iterations seeded with previous r
        v2f d = z + ONEv;
        v2f ne = vfma(-d, r, TWOv); r = r * ne;
        ne = vfma(-d, r, TWOv);     r = r * ne;
    };

    int i = 1;
    if (N >= 2*CH) {
        float rawA[CH], rawB[CH];
        int nch = N / CH;
        int npair = nch / 2;
        int lim = N + 1 - CH;

#pragma unroll
        for (int m = 0; m < CH; ++m) rawA[m] = trow[1 + m];   // chunk 0

        float2* op = (float2*)orow + 1;
        for (int p = 0; p < npair; ++p) {
            int c = 2*p;
            {   // process chunk c (rawA), prefetch chunk c+1 into rawB
                int base = (c + 1)*CH + 1; if (base > lim) base = lim;
                const float* lp = trow + base;
#pragma unroll
                for (int m = 0; m < CH; ++m) {
                    rawB[m] = lp[m];
                    if ((m % RS) == 0) slow_step(rawA[m], op[m]);
                    else               fast_step(rawA[m], op[m]);
                }
                op += CH;
            }
            {   // process chunk c+1 (rawB), prefetch chunk c+2 into rawA
                int base = (c + 2)*CH + 1; if (base > lim) base = lim;
                const float* lp = trow + base;
#pragma unroll
                for (int m = 0; m < CH; ++m) {
                    rawA[m] = lp[m];
                    if ((m % RS) == 0) slow_step(rawB[m], op[m]);
                    else               fast_step(rawB[m], op[m]);
                }
                op += CH;
            }
        }
        i = 2*CH*npair + 1;
    }
    // scalar tail (not hit for N=2048): all exact steps
    for (; i <= N; ++i) {
        slow_step(trow[i], *(float2*)(orow + 2*(size_t)i));
    }
}

extern "C" void kernel_launch(void* const* d_in, const int* in_sizes, int n_in,
                              void* d_out, int out_size, void* d_ws, size_t ws_size,
                              hipStream_t stream) {
    const float* t  = (const float*)d_in[0];
    const float* Vs = (const float*)d_in[1];
    const float* Tm = (const float*)d_in[2];
    const float* C0 = (const float*)d_in[3];
    const float* R0 = (const float*)d_in[4];
    const float* W1 = (const float*)d_in[5];
    const float* b1 = (const float*)d_in[6];
    const float* W2 = (const float*)d_in[7];
    const float* b2 = (const float*)d_in[8];
    float* out = (float*)d_out;

    int B = in_sizes[1];
    int N = in_sizes[0] / B - 1;

    int threads = B * LPE;
    dim3 block(256);
    dim3 grid((threads + 255) / 256);
    hipLaunchKernelGGL(ode_scan, grid, block, 0, stream,
                       t, Vs, Tm, C0, R0, W1, b1, W2, b2, out, B, N);
}